// Round 11
// baseline (68.044 us; speedup 1.0000x reference)
//
#include <hip/hip_runtime.h>
#include <math.h>

#define HH 352
#define WW 352
#define WPR 11                     // WW/32, exact (352 = 11*32)
#define INF_I (1 << 30)

// ---------------------------------------------------------------------------
// Kernel 1: pack target!=0 into a bitmask, 1 bit/pixel, row-major.
// 62 KB total for B=4 -> L2-resident for the main kernel. Wave ballot gives
// 64 bits; lanes 0/32 store the two u32 words. Thread 0 writes a pad word
// so the main kernel's unconditional mrow[u2+1] load never faults.
// ---------------------------------------------------------------------------
__global__ __launch_bounds__(256) void pack_kernel(const float* __restrict__ target,
                                                   unsigned int* __restrict__ mask, int N)
{
    int idx = blockIdx.x * 256 + threadIdx.x;
    bool bit = (target[idx] != 0.0f);
    unsigned long long bal = __ballot(bit);
    int lane = threadIdx.x & 63;
    if (lane == 0)       mask[idx >> 5] = (unsigned int)bal;
    else if (lane == 32) mask[idx >> 5] = (unsigned int)(bal >> 32);
    if (idx == 0) mask[N >> 5] = 0u;   // pad word
}

// ---------------------------------------------------------------------------
// Kernel 2: one thread per pixel, everything from the bitmask.
// d2 = min over opposite-valued pixels of (di^2+dj^2) == |sdt|^2 exactly.
// 5x5 window from 5 rows x 5-bit extracts (funnel shift of two mask words);
// per row min-dx^2 via 3 constant masks (center=4, 0b01010=+1, 0b10001=+4).
// Exact when the window hits (<=8 < 9 <= outside); boundary bits are masked
// AFTER the opposite-XOR so shifted-in zeros / pad garbage never become
// candidates. Rare exact expanding-ring fallback on raw target (P~2^-24).
// w = exp(-sqrt(d2)/5); no-opposite => w=0 (matches reference underflow).
// Block-reduce (min w, max w, sum bce, sum bce*w); loss separability:
// sum bce*(1+0.5*wn) = S1 + 0.5*(SW - wmin*S1)/den.
// ---------------------------------------------------------------------------
__global__ __launch_bounds__(256) void fusedbit_kernel(const float* __restrict__ pred,
                                                       const float* __restrict__ target,
                                                       const unsigned int* __restrict__ mask,
                                                       float* __restrict__ bmin,
                                                       float* __restrict__ bmax,
                                                       float* __restrict__ bs1,
                                                       float* __restrict__ bsw)
{
    const int HW = HH * WW;
    int idx = blockIdx.x * 256 + threadIdx.x;
    float p = pred[idx];                    // the only HBM stream; issue first
    int b = idx / HW;
    int r0 = idx - b * HW;
    int i = r0 / WW;
    int j = r0 - i * WW;
    const unsigned int* mimg = mask + b * (HH * WPR);

    unsigned int cw = mimg[i * WPR + (j >> 5)];
    bool fg = (cw >> (j & 31)) & 1u;

    // valid dx positions (bit p <-> dx = p-2); both edges can't trigger at once
    unsigned int valid = 31u;
    if (j < 2)   valid &= (31u << (2 - j)) & 31u;
    if (j > 349) valid &= 31u >> (j - 349);

    int best = INF_I;
    int s = j - 2;
    #pragma unroll
    for (int dy = -2; dy <= 2; ++dy) {
        int iy = i + dy;
        bool rowok = (iy >= 0) && (iy < HH);
        int iyc = rowok ? iy : (iy < 0 ? 0 : HH - 1);
        const unsigned int* mrow = mimg + iyc * WPR;
        unsigned int w5;
        if (j >= 2) {
            int u2 = s >> 5, sh = s & 31;
            unsigned long long M = (unsigned long long)mrow[u2] |
                                   ((unsigned long long)mrow[u2 + 1] << 32);
            w5 = (unsigned int)(M >> sh) & 31u;
        } else {
            w5 = (mrow[0] << (2 - j)) & 31u;
        }
        unsigned int opp = (fg ? ~w5 : w5) & valid;
        if (!rowok) opp = 0u;
        const int dy2 = dy * dy;            // compile-time per unrolled iter
        int rowd2 = (opp & 4u)  ? dy2 :
                    (opp & 10u) ? dy2 + 1 :
                    (opp & 17u) ? dy2 + 4 : INF_I;
        best = rowd2 < best ? rowd2 : best;
    }

    if (best == INF_I) {                    // rare exact fallback (P ~ 2^-24/pixel)
        const float* timg = target + b * HW;
        for (int rad = 3; rad <= 351; ++rad) {
            if (rad * rad >= best) break;
            int y0 = i - rad, y1 = i + rad, x0 = j - rad, x1 = j + rad;
            int xa = x0 < 0 ? 0 : x0, xb = x1 >= WW ? WW - 1 : x1;
            for (int pass = 0; pass < 2; ++pass) {
                int iy = pass ? y1 : y0;
                if (iy < 0 || iy >= HH) continue;
                int dy2 = (iy - i) * (iy - i);
                for (int jx = xa; jx <= xb; ++jx) {
                    if ((timg[iy * WW + jx] != 0.0f) != fg) {
                        int cd = dy2 + (jx - j) * (jx - j);
                        if (cd < best) best = cd;
                    }
                }
            }
            int ya = y0 + 1 < 0 ? 0 : y0 + 1, yb = y1 - 1 >= HH ? HH - 1 : y1 - 1;
            for (int pass = 0; pass < 2; ++pass) {
                int jx = pass ? x1 : x0;
                if (jx < 0 || jx >= WW) continue;
                int dx2 = (jx - j) * (jx - j);
                for (int iy = ya; iy <= yb; ++iy) {
                    if ((timg[iy * WW + jx] != 0.0f) != fg) {
                        int cd = dx2 + (iy - i) * (iy - i);
                        if (cd < best) best = cd;
                    }
                }
            }
        }
    }

    float w = (best == INF_I) ? 0.0f : expf(-sqrtf((float)best) * 0.2f);  // SIGMA=5
    float t = fg ? 1.0f : 0.0f;             // target is exactly {0,1}
    float bce = fmaxf(p, 0.0f) - p * t + log1pf(expf(-fabsf(p)));
    float bw = bce * w;

    // block reduce (4 waves): min w, max w, sum bce, sum bce*w
    float lmin = w, lmax = w, ls1 = bce, lsw = bw;
    #pragma unroll
    for (int off = 32; off > 0; off >>= 1) {
        lmin = fminf(lmin, __shfl_down(lmin, off));
        lmax = fmaxf(lmax, __shfl_down(lmax, off));
        ls1 += __shfl_down(ls1, off);
        lsw += __shfl_down(lsw, off);
    }
    __shared__ float s4[4][4];
    int wid = threadIdx.x >> 6;
    if ((threadIdx.x & 63) == 0) {
        s4[0][wid] = lmin; s4[1][wid] = lmax; s4[2][wid] = ls1; s4[3][wid] = lsw;
    }
    __syncthreads();
    if (threadIdx.x == 0) {
        float m0 = s4[0][0], m1 = s4[1][0], a = s4[2][0], c2 = s4[3][0];
        #pragma unroll
        for (int q = 1; q < 4; ++q) {
            m0 = fminf(m0, s4[0][q]);
            m1 = fmaxf(m1, s4[1][q]);
            a += s4[2][q];
            c2 += s4[3][q];
        }
        bmin[blockIdx.x] = m0; bmax[blockIdx.x] = m1;
        bs1[blockIdx.x] = a;   bsw[blockIdx.x] = c2;
    }
}

// ---------------------------------------------------------------------------
// Final: 1 block, wave wv handles sample wv. Per sample: reduce nPB entries ->
// wmin, wmax, S1, SW (f64 sums); loss_b = S1 + 0.5*(SW - wmin*S1)/den;
// sum across samples; mean -> out.
// ---------------------------------------------------------------------------
__global__ __launch_bounds__(256) void final2_kernel(const float* __restrict__ bmin,
                                                     const float* __restrict__ bmax,
                                                     const float* __restrict__ bs1,
                                                     const float* __restrict__ bsw,
                                                     float* __restrict__ out,
                                                     int B, int nPB, double invN)
{
    __shared__ double sl[4];
    int wid = threadIdx.x >> 6, lane = threadIdx.x & 63;
    double mysum = 0.0;
    for (int b = wid; b < B; b += 4) {
        float lmin = 3e38f, lmax = 0.0f;
        double ds1 = 0.0, dsw = 0.0;
        for (int t = lane; t < nPB; t += 64) {
            int o = b * nPB + t;
            lmin = fminf(lmin, bmin[o]);
            lmax = fmaxf(lmax, bmax[o]);
            ds1 += (double)bs1[o];
            dsw += (double)bsw[o];
        }
        #pragma unroll
        for (int off = 32; off > 0; off >>= 1) {
            lmin = fminf(lmin, __shfl_down(lmin, off));
            lmax = fmaxf(lmax, __shfl_down(lmax, off));
            ds1 += __shfl_down(ds1, off);
            dsw += __shfl_down(dsw, off);
        }
        if (lane == 0) {
            double wmin = (double)lmin;
            double den  = (double)lmax - wmin + 1e-6;
            mysum += ds1 + 0.5 * (dsw - wmin * ds1) / den;
        }
    }
    if (lane == 0) sl[wid] = mysum;
    __syncthreads();
    if (threadIdx.x == 0) {
        double tot = 0.0;
        #pragma unroll
        for (int q = 0; q < 4; ++q) tot += sl[q];
        out[0] = (float)(tot * invN);
    }
}

extern "C" void kernel_launch(void* const* d_in, const int* in_sizes, int n_in,
                              void* d_out, int out_size, void* d_ws, size_t ws_size,
                              hipStream_t stream)
{
    const float* pred   = (const float*)d_in[0];
    const float* target = (const float*)d_in[1];
    float* out = (float*)d_out;

    const int N = in_sizes[0];           // B*1*H*W = 495616
    const int B = N / (HH * WW);         // = 4
    const int nBlk = N / 256;            // 1936, exact
    const int nPB = (HH * WW) / 256;     // 484 blocks per sample (block-uniform)

    float* bmin = (float*)d_ws;
    float* bmax = bmin + nBlk;
    float* bs1  = bmax + nBlk;
    float* bsw  = bs1 + nBlk;
    unsigned int* mask = (unsigned int*)(bsw + nBlk);   // (N/32)+1 u32, 4B-aligned

    hipLaunchKernelGGL(pack_kernel, dim3(nBlk), dim3(256), 0, stream,
                       target, mask, N);

    hipLaunchKernelGGL(fusedbit_kernel, dim3(nBlk), dim3(256), 0, stream,
                       pred, target, mask, bmin, bmax, bs1, bsw);

    hipLaunchKernelGGL(final2_kernel, dim3(1), dim3(256), 0, stream,
                       bmin, bmax, bs1, bsw, out, B, nPB, 1.0 / (double)N);
}

// Round 12
// 65.156 us; speedup vs baseline: 1.0443x; 1.0443x over previous
//
#include <hip/hip_runtime.h>
#include <math.h>

#define HH 352
#define WW 352
#define WPR 11                      // words per row = 352/32
#define NWORDS (HH * WPR)           // words per image
#define INF_I (1 << 30)

// ---------------------------------------------------------------------------
// Kernel 1: pack target!=0 into a row-major bitmask, one u32 WORD per thread
// (32 consecutive pixels, 8 float4 loads). 61 WGs. Thread 0 writes a pad word
// so the main kernel's unconditional mrow[u2+1] load never reads junk-crash.
// ---------------------------------------------------------------------------
__global__ __launch_bounds__(256) void pack_kernel(const float* __restrict__ target,
                                                   unsigned int* __restrict__ mask,
                                                   int nWords)
{
    int w = blockIdx.x * 256 + threadIdx.x;
    if (w >= nWords) return;
    const float4* t4 = (const float4*)(target + (w << 5));
    unsigned int word = 0u;
    #pragma unroll
    for (int k = 0; k < 8; ++k) {
        float4 v = t4[k];
        unsigned int nib = (v.x != 0.f ? 1u : 0u) | (v.y != 0.f ? 2u : 0u) |
                           (v.z != 0.f ? 4u : 0u) | (v.w != 0.f ? 8u : 0u);
        word |= nib << (4 * k);
    }
    mask[w] = word;
    if (w == 0) mask[nWords] = 0u;      // pad word
}

// ---------------------------------------------------------------------------
// Kernel 2: 4 pixels per thread (one row-aligned group; 352%4==0), 484 WGs.
// d2 = min over opposite pixels of (di^2+dj^2) == |sdt|^2 exactly (one of
// dist_fg/dist_bg is 0 everywhere). 5x5 window per pixel from ONE 8-bit
// row-extract shared by the 4 pixels; per-row min-dx^2 via 3 constant masks.
// Window hit => exact (<=8 < 9 <= anything outside); boundary bits masked
// AFTER the opposite-XOR (shifted-in zeros / next-row garbage can't become
// candidates). Rare exact expanding-ring fallback on raw target (P~2^-24).
// w = exp(-sqrt(d2)/5); no-opposite => w=0 (matches reference underflow).
// Block reduce (min w, max w, sum bce, sum bce*w) -> 4 plain floats/block.
// Loss separability: sum bce*(1+0.5*wn) = S1 + 0.5*(SW - wmin*S1)/den.
// ---------------------------------------------------------------------------
__global__ __launch_bounds__(256) void fused4_kernel(const float* __restrict__ pred,
                                                     const float* __restrict__ target,
                                                     const unsigned int* __restrict__ mask,
                                                     float* __restrict__ bmin,
                                                     float* __restrict__ bmax,
                                                     float* __restrict__ bs1,
                                                     float* __restrict__ bsw)
{
    const int HW = HH * WW;
    int g = blockIdx.x * 256 + threadIdx.x;     // 4-pixel group id
    int px = g << 2;
    int b = px / HW;
    int r0 = px - b * HW;
    int i = r0 / WW;
    int j0 = r0 - i * WW;                       // multiple of 4; group stays in row

    float4 p4 = *(const float4*)(pred + px);    // only HBM stream; issue first
    const unsigned int* mimg = mask + b * NWORDS;

    // center-row 8-bit window (cols j0-2 .. j0+5)
    int s = j0 - 2;
    unsigned int w8[5];
    #pragma unroll
    for (int dy = -2; dy <= 2; ++dy) {
        int iy = i + dy;
        bool rowok = (iy >= 0) && (iy < HH);
        int iyc = rowok ? iy : 0;
        const unsigned int* mrow = mimg + iyc * WPR;
        unsigned int v;
        if (j0 == 0) {
            v = (mrow[0] << 2) & 0xFCu;         // cols 0..5 at bits 2..7
        } else {
            int u2 = s >> 5, sh = s & 31;
            unsigned long long M = (unsigned long long)mrow[u2] |
                                   ((unsigned long long)mrow[u2 + 1] << 32);
            v = (unsigned int)(M >> sh) & 0xFFu;
        }
        w8[dy + 2] = rowok ? v : 0xDEADu;       // flag; per-q handled below
        if (!rowok) w8[dy + 2] = 0x100u;        // sentinel: row invalid
    }
    unsigned int c8 = w8[2];                    // center row bits (always valid)

    int best[4];
    float wv[4];
    bool fgq[4];
    #pragma unroll
    for (int q = 0; q < 4; ++q) {
        int j = j0 + q;
        bool fg = (c8 >> (q + 2)) & 1u;
        fgq[q] = fg;
        unsigned int valid = 31u;
        if (j < 2)   valid &= (31u << (2 - j)) & 31u;
        if (j > WW - 3) valid &= 31u >> (j - (WW - 3));
        int bq = INF_I;
        #pragma unroll
        for (int dy = -2; dy <= 2; ++dy) {
            unsigned int rw = w8[dy + 2];
            const int dy2 = dy * dy;
            unsigned int w5 = (rw >> q) & 31u;
            unsigned int opp = (fg ? ~w5 : w5) & valid;
            if (rw & 0x100u) opp = 0u;          // invalid row
            int rowd2 = (opp & 4u)  ? dy2 :
                        (opp & 10u) ? dy2 + 1 :
                        (opp & 17u) ? dy2 + 4 : INF_I;
            bq = rowd2 < bq ? rowd2 : bq;
        }
        best[q] = bq;
    }

    // rare exact fallback (P ~ 2^-24 per pixel)
    #pragma unroll
    for (int q = 0; q < 4; ++q) {
        if (best[q] == INF_I) {
            const float* timg = target + b * HW;
            int j = j0 + q;
            bool fg = fgq[q];
            int bq = best[q];
            for (int rad = 3; rad <= 351; ++rad) {
                if (rad * rad >= bq) break;
                int y0 = i - rad, y1 = i + rad, x0 = j - rad, x1 = j + rad;
                int xa = x0 < 0 ? 0 : x0, xb = x1 >= WW ? WW - 1 : x1;
                for (int pass = 0; pass < 2; ++pass) {
                    int iy = pass ? y1 : y0;
                    if (iy < 0 || iy >= HH) continue;
                    int dy2 = (iy - i) * (iy - i);
                    for (int jx = xa; jx <= xb; ++jx)
                        if ((timg[iy * WW + jx] != 0.0f) != fg) {
                            int cd = dy2 + (jx - j) * (jx - j);
                            if (cd < bq) bq = cd;
                        }
                }
                int ya = y0 + 1 < 0 ? 0 : y0 + 1, yb = y1 - 1 >= HH ? HH - 1 : y1 - 1;
                for (int pass = 0; pass < 2; ++pass) {
                    int jx = pass ? x1 : x0;
                    if (jx < 0 || jx >= WW) continue;
                    int dx2 = (jx - j) * (jx - j);
                    for (int iy = ya; iy <= yb; ++iy)
                        if ((timg[iy * WW + jx] != 0.0f) != fg) {
                            int cd = dx2 + (iy - i) * (iy - i);
                            if (cd < bq) bq = cd;
                        }
                }
            }
            best[q] = bq;
        }
    }

    float lmin = 3e38f, lmax = 0.0f, ls1 = 0.0f, lsw = 0.0f;
    float pv[4] = {p4.x, p4.y, p4.z, p4.w};
    #pragma unroll
    for (int q = 0; q < 4; ++q) {
        float w = (best[q] == INF_I) ? 0.0f
                                     : expf(-sqrtf((float)best[q]) * 0.2f); // SIGMA=5
        float p = pv[q];
        float t = fgq[q] ? 1.0f : 0.0f;
        float bce = fmaxf(p, 0.0f) - p * t + log1pf(expf(-fabsf(p)));
        lmin = fminf(lmin, w);
        lmax = fmaxf(lmax, w);
        ls1 += bce;
        lsw += bce * w;
    }

    // block reduce (4 waves): min w, max w, sum bce, sum bce*w
    #pragma unroll
    for (int off = 32; off > 0; off >>= 1) {
        lmin = fminf(lmin, __shfl_down(lmin, off));
        lmax = fmaxf(lmax, __shfl_down(lmax, off));
        ls1 += __shfl_down(ls1, off);
        lsw += __shfl_down(lsw, off);
    }
    __shared__ float s4[4][4];
    int wid = threadIdx.x >> 6;
    if ((threadIdx.x & 63) == 0) {
        s4[0][wid] = lmin; s4[1][wid] = lmax; s4[2][wid] = ls1; s4[3][wid] = lsw;
    }
    __syncthreads();
    if (threadIdx.x == 0) {
        float m0 = s4[0][0], m1 = s4[1][0], a = s4[2][0], c2 = s4[3][0];
        #pragma unroll
        for (int t2 = 1; t2 < 4; ++t2) {
            m0 = fminf(m0, s4[0][t2]);
            m1 = fmaxf(m1, s4[1][t2]);
            a += s4[2][t2];
            c2 += s4[3][t2];
        }
        bmin[blockIdx.x] = m0; bmax[blockIdx.x] = m1;
        bs1[blockIdx.x] = a;   bsw[blockIdx.x] = c2;
    }
}

// ---------------------------------------------------------------------------
// Final: 1 block, wave wv handles sample wv. Reduce nPB=121 per-block entries
// -> wmin, wmax, S1, SW (f64 sums); loss_b = S1 + 0.5*(SW - wmin*S1)/den;
// sum across samples; mean -> out.
// ---------------------------------------------------------------------------
__global__ __launch_bounds__(256) void final2_kernel(const float* __restrict__ bmin,
                                                     const float* __restrict__ bmax,
                                                     const float* __restrict__ bs1,
                                                     const float* __restrict__ bsw,
                                                     float* __restrict__ out,
                                                     int B, int nPB, double invN)
{
    __shared__ double sl[4];
    int wid = threadIdx.x >> 6, lane = threadIdx.x & 63;
    double mysum = 0.0;
    for (int b = wid; b < B; b += 4) {
        float lmin = 3e38f, lmax = 0.0f;
        double ds1 = 0.0, dsw = 0.0;
        for (int t = lane; t < nPB; t += 64) {
            int o = b * nPB + t;
            lmin = fminf(lmin, bmin[o]);
            lmax = fmaxf(lmax, bmax[o]);
            ds1 += (double)bs1[o];
            dsw += (double)bsw[o];
        }
        #pragma unroll
        for (int off = 32; off > 0; off >>= 1) {
            lmin = fminf(lmin, __shfl_down(lmin, off));
            lmax = fmaxf(lmax, __shfl_down(lmax, off));
            ds1 += __shfl_down(ds1, off);
            dsw += __shfl_down(dsw, off);
        }
        if (lane == 0) {
            double wmin = (double)lmin;
            double den  = (double)lmax - wmin + 1e-6;
            mysum += ds1 + 0.5 * (dsw - wmin * ds1) / den;
        }
    }
    if (lane == 0) sl[wid] = mysum;
    __syncthreads();
    if (threadIdx.x == 0) {
        double tot = 0.0;
        #pragma unroll
        for (int q = 0; q < 4; ++q) tot += sl[q];
        out[0] = (float)(tot * invN);
    }
}

extern "C" void kernel_launch(void* const* d_in, const int* in_sizes, int n_in,
                              void* d_out, int out_size, void* d_ws, size_t ws_size,
                              hipStream_t stream)
{
    const float* pred   = (const float*)d_in[0];
    const float* target = (const float*)d_in[1];
    float* out = (float*)d_out;

    const int N = in_sizes[0];            // 495616
    const int B = N / (HH * WW);          // 4
    const int nGrp = N / 4;               // 123904 4-pixel groups
    const int nBlk = nGrp / 256;          // 484 main blocks (exact)
    const int nPB  = (HH * WW) / 1024;    // 121 blocks per sample (exact)
    const int nWords = N / 32;            // 15488

    float* bmin = (float*)d_ws;
    float* bmax = bmin + nBlk;
    float* bs1  = bmax + nBlk;
    float* bsw  = bs1 + nBlk;
    unsigned int* mask = (unsigned int*)(bsw + nBlk);   // nWords+1 u32

    hipLaunchKernelGGL(pack_kernel, dim3((nWords + 255) / 256), dim3(256), 0, stream,
                       target, mask, nWords);

    hipLaunchKernelGGL(fused4_kernel, dim3(nBlk), dim3(256), 0, stream,
                       pred, target, mask, bmin, bmax, bs1, bsw);

    hipLaunchKernelGGL(final2_kernel, dim3(1), dim3(256), 0, stream,
                       bmin, bmax, bs1, bsw, out, B, nPB, 1.0 / (double)N);
}